// Round 1
// 245.370 us; speedup vs baseline: 1.1177x; 1.1177x over previous
//
#include <hip/hip_runtime.h>

#define N_NODES 100000
#define N_EDGES 1250000
#define D 64

#define BSHIFT 9
#define BUCKETS 196          // ceil(100000 / 512)
#define CAP 8192             // srtTmp capacity per bucket (mean 6378, +22 sigma)
#define CHUNK 4096           // edges per bucketA block
#define PA_BLOCKS ((N_EDGES + CHUNK - 1) / CHUNK)   // 306
#define LCAP 64              // LDS list capacity per bucket per chunk (mean 21)

typedef long long ll;

// ---------- init: cursor[b] = b*CAP; zero-pad srt tail ----------
__global__ void init_kernel(int* __restrict__ cursor, int* __restrict__ srt) {
    int t = threadIdx.x;
    if (t < BUCKETS) cursor[t] = t * CAP;
    if (t < 8) srt[N_EDGES + t] = 0;
}

// ---------- pass A: bin edges into 196 coarse buckets, coalesced flushes ----------
__global__ __launch_bounds__(256) void bucketA_kernel(const int* __restrict__ src,
                                                      const int* __restrict__ dst,
                                                      int* __restrict__ cursor,
                                                      int* __restrict__ tmp) {
    __shared__ int lcnt[BUCKETS];
    __shared__ int list[BUCKETS * LCAP];   // ~50 KB
    int tid = threadIdx.x;
    for (int b = tid; b < BUCKETS; b += 256) lcnt[b] = 0;
    __syncthreads();

    int base = blockIdx.x * CHUNK;
    int nE = min(CHUNK, N_EDGES - base);
    for (int i = tid; i < nE; i += 256) {
        int e = base + i;
        int s = src[e], d = dst[e];
        int b = d >> BSHIFT;
        int p = atomicAdd(&lcnt[b], 1);            // LDS atomic, cheap
        list[b * LCAP + p] = s | ((d & 511) << 17); // src:17b, dstLow:9b
    }
    __syncthreads();

    // one global atomic per (block, bucket); flush run is contiguous
    for (int b = tid; b < BUCKETS; b += 256) {
        int c = lcnt[b];
        if (c > 0) {
            int gb = atomicAdd(&cursor[b], c);
            for (int k = 0; k < c; ++k) tmp[gb + k] = list[b * LCAP + k];
        }
    }
}

// ---------- tiny scan: bucket bases from cursor counts ----------
__global__ void scanSmall_kernel(const int* __restrict__ cursor, int* __restrict__ bbase) {
    __shared__ int s[256];
    int tid = threadIdx.x;
    int x = (tid < BUCKETS) ? (cursor[tid] - tid * CAP) : 0;
    s[tid] = x;
    __syncthreads();
    for (int off = 1; off < 256; off <<= 1) {
        int v = (tid >= off) ? s[tid - off] : 0;
        __syncthreads();
        s[tid] += v;
        __syncthreads();
    }
    if (tid < BUCKETS) bbase[tid] = s[tid] - x;   // exclusive
}

// ---------- pass B: per-bucket local sort -> final srt + offs ----------
__global__ __launch_bounds__(512) void bucketB_kernel(const int* __restrict__ cursor,
                                                      const int* __restrict__ bbase,
                                                      const int* __restrict__ tmp,
                                                      int* __restrict__ srt,
                                                      int* __restrict__ offs) {
    __shared__ int hist[512];
    __shared__ int s[512];
    __shared__ int cur[512];
    int b = blockIdx.x, tid = threadIdx.x;
    int cbase = b * CAP;
    int cnt = cursor[b] - cbase;
    int gbase = bbase[b];

    hist[tid] = 0;
    __syncthreads();
    for (int i = tid; i < cnt; i += 512) {
        int ln = tmp[cbase + i] >> 17;
        atomicAdd(&hist[ln], 1);          // LDS atomic, avg 12.5/node
    }
    __syncthreads();

    // inclusive Hillis-Steele over 512 -> exclusive
    int x = hist[tid];
    s[tid] = x;
    __syncthreads();
    for (int off = 1; off < 512; off <<= 1) {
        int v = (tid >= off) ? s[tid - off] : 0;
        __syncthreads();
        s[tid] += v;
        __syncthreads();
    }
    int excl = s[tid] - x;
    cur[tid] = excl;

    int node0 = b << BSHIFT;
    int nloc = min(512, N_NODES - node0);
    if (tid < nloc) offs[node0 + tid] = gbase + excl;   // coalesced
    __syncthreads();

    for (int i = tid; i < cnt; i += 512) {
        int v = tmp[cbase + i];            // L2-hot (second read)
        int ln = v >> 17;
        int p = atomicAdd(&cur[ln], 1);
        srt[gbase + p] = v & 0x1FFFF;      // random within 25KB window, L2-buffered
    }
}

// ---------- fused pull + linear: float4 gather, 4 edges per load instr ----------
// Lane layout: sub = lane&15 covers the 64-dim row as float4 (16B/lane);
// g = lane>>4 selects one of 4 edges per batch slot. A 16-edge batch issues
// 4 idx loads + 4 float4 gathers per lane (4 KB/wave in flight) instead of
// 16 scalar idx loads + 16 scalar gathers + ~56 addr-VALU. Tail edges are
// clamped to end-1 (L1-hit duplicate) and masked with fmaf.
#define NBLK 2048
__global__ __launch_bounds__(256) void fused_layer(const float* __restrict__ h,
                                                   const int* __restrict__ offs,
                                                   const int* __restrict__ srt,
                                                   const float* __restrict__ W1,
                                                   const float* __restrict__ b1,
                                                   float* __restrict__ out) {
    __shared__ __align__(16) float rowbuf[4][64];
    const int tid  = threadIdx.x;
    const int lane = tid & 63;
    const int wid  = tid >> 6;
    const int g    = lane >> 4;      // edge slot 0..3 within batch
    const int sub  = lane & 15;      // float4 quad within the row
    const int gw   = blockIdx.x * 4 + wid;
    const int GW   = NBLK * 4;

    float4 Wreg[16];
    const float4* wrow = (const float4*)(W1 + lane * D);
#pragma unroll
    for (int i = 0; i < 16; ++i) Wreg[i] = wrow[i];
    const float bj = b1[lane];

    for (int n = gw; n < N_NODES; n += GW) {
        const int beg = offs[n];
        const int end = (n == N_NODES - 1) ? N_EDGES : offs[n + 1];
        const int em  = end - 1;

        float ax = 0.f, ay = 0.f, az = 0.f, aw = 0.f;
        for (int eb = beg; eb < end; eb += 16) {
            const int e0 = eb + (g << 2);
            const int c0 = min(e0,     em);
            const int c1 = min(e0 + 1, em);
            const int c2 = min(e0 + 2, em);
            const int c3 = min(e0 + 3, em);
            const int s0 = srt[c0];
            const int s1 = srt[c1];
            const int s2 = srt[c2];
            const int s3 = srt[c3];
            const float4 v0 = *((const float4*)(h + (ll)s0 * D) + sub);
            const float4 v1 = *((const float4*)(h + (ll)s1 * D) + sub);
            const float4 v2 = *((const float4*)(h + (ll)s2 * D) + sub);
            const float4 v3 = *((const float4*)(h + (ll)s3 * D) + sub);
            const float m0 = (e0     < end) ? 1.f : 0.f;
            const float m1 = (e0 + 1 < end) ? 1.f : 0.f;
            const float m2 = (e0 + 2 < end) ? 1.f : 0.f;
            const float m3 = (e0 + 3 < end) ? 1.f : 0.f;
            ax = fmaf(v0.x, m0, ax); ay = fmaf(v0.y, m0, ay);
            az = fmaf(v0.z, m0, az); aw = fmaf(v0.w, m0, aw);
            ax = fmaf(v1.x, m1, ax); ay = fmaf(v1.y, m1, ay);
            az = fmaf(v1.z, m1, az); aw = fmaf(v1.w, m1, aw);
            ax = fmaf(v2.x, m2, ax); ay = fmaf(v2.y, m2, ay);
            az = fmaf(v2.z, m2, az); aw = fmaf(v2.w, m2, aw);
            ax = fmaf(v3.x, m3, ax); ay = fmaf(v3.y, m3, ay);
            az = fmaf(v3.z, m3, az); aw = fmaf(v3.w, m3, aw);
        }

        // sum the 4 edge-groups: lanes {sub, sub+16, sub+32, sub+48}
        ax += __shfl_xor(ax, 16); ay += __shfl_xor(ay, 16);
        az += __shfl_xor(az, 16); aw += __shfl_xor(aw, 16);
        ax += __shfl_xor(ax, 32); ay += __shfl_xor(ay, 32);
        az += __shfl_xor(az, 32); aw += __shfl_xor(aw, 32);

        if (g == 0) {
            float4 t; t.x = ax; t.y = ay; t.z = az; t.w = aw;
            *((float4*)rowbuf[wid] + sub) = t;   // wave-internal, in-order DS pipe
        }

        float o = bj;
        const float4* rb = (const float4*)rowbuf[wid];
#pragma unroll
        for (int k4 = 0; k4 < 16; ++k4) {
            float4 r = rb[k4];                    // broadcast read, conflict-free
            o += r.x * Wreg[k4].x + r.y * Wreg[k4].y
               + r.z * Wreg[k4].z + r.w * Wreg[k4].w;
        }
        out[(ll)n * D + lane] = o;
    }
}

extern "C" void kernel_launch(void* const* d_in, const int* in_sizes, int n_in,
                              void* d_out, int out_size, void* d_ws, size_t ws_size,
                              hipStream_t stream) {
    const float* x  = (const float*)d_in[0];   // [N, D]
    const int* edge = (const int*)d_in[1];     // [2, E]: src row then dst row
    const float* W1 = (const float*)d_in[2];   // [D, D]
    const float* b1 = (const float*)d_in[3];   // [D]

    const int* src = edge;
    const int* dst = edge + N_EDGES;

    float* out = (float*)d_out;                    // output 0: [N, D]
    float* hid = (float*)d_out + (ll)N_NODES * D;  // output 1: [N, D]

    // workspace layout (~12 MB; >=25.6 MB proven available in round 1)
    char* ws = (char*)d_ws;
    int* cursor = (int*)ws;  ws += 1024;                                   // [196]
    int* bbase  = (int*)ws;  ws += 1024;                                   // [196]
    int* offs   = (int*)ws;  ws += ((size_t)N_NODES * 4 + 255) & ~255ull;  // [N]
    int* srt    = (int*)ws;  ws += ((size_t)(N_EDGES + 8) * 4 + 255) & ~255ull;  // [E+8]
    int* tmp    = (int*)ws;                                                // [196*CAP]

    // ---- build CSR via two-pass bucket sort (once; reused by both layers) ----
    init_kernel<<<1, 256, 0, stream>>>(cursor, srt);
    bucketA_kernel<<<PA_BLOCKS, 256, 0, stream>>>(src, dst, cursor, tmp);
    scanSmall_kernel<<<1, 256, 0, stream>>>(cursor, bbase);
    bucketB_kernel<<<BUCKETS, 512, 0, stream>>>(cursor, bbase, tmp, srt, offs);

    // ---- layer 1: hid = segsum(x) @ W1^T + b1 ----
    fused_layer<<<NBLK, 256, 0, stream>>>(x, offs, srt, W1, b1, hid);
    // ---- layer 2: out = segsum(hid) @ W1^T + b1 ----
    fused_layer<<<NBLK, 256, 0, stream>>>(hid, offs, srt, W1, b1, out);
}